// Round 1
// baseline (28.583 us; speedup 1.0000x reference)
//
#include <hip/hip_runtime.h>
#include <math.h>

// BlockwiseQuantizationOptim: 1024x1024 f32 weight, 64 blocks of 128x128,
// L=256 levels, T=100, soft quantization + column-binned entropy.
//
// Closed-form softmax over uniform levels: e_l = r^{|p-l|}, r = exp(-T/255).
//   S  = r^f * A[k] + r^{1-f} * A[254-k]
//   W  = r^f * (k*A[k] - B[k]) + r^{1-f} * ((k+1)*A[254-k] + B[254-k])
// with A[k] = sum_{m=0..k} r^m, B[k] = sum_{m=0..k} m r^m (LDS tables).
// bin_mass via 2 impulse deposits per element + geometric scans per column.

#define NTHREADS 256
#define COLS 16      // columns per workgroup slab
#define LVL 256
#define PITCH 257    // +1 pad to break scan-phase bank conflicts

__global__ __launch_bounds__(NTHREADS)
void bq_main(const float* __restrict__ Wt,
             const float* __restrict__ wmin_in,
             const float* __restrict__ wmax_in,
             float* __restrict__ dq_out,
             float* __restrict__ partials)
{
    __shared__ float tabA[LVL];
    __shared__ float tabB[LVL];
    __shared__ float depD[COLS][PITCH];   // down-chain deposits -> scanned D
    __shared__ float depU[COLS][PITCH];   // up-chain deposits   -> scanned U
    __shared__ float carry[2][COLS][8];
    __shared__ float wred[4];

    const int tid  = threadIdx.x;
    const int wg   = blockIdx.x;
    const int n    = wg >> 3;     // block id 0..63
    const int slab = wg & 7;      // 16-col slab within block

    const float Td   = 100.0f / 255.0f;
    const float L2R  = -Td * 1.4426950408889634f;  // log2(r)
    const float r    = exp2f(L2R);
    const float inv1mr = 1.0f / (1.0f - r);

    // geometric tables: A[k], B[k]
    {
        const float rk1 = exp2f(L2R * (float)(tid + 1));       // r^{k+1}
        tabA[tid] = (1.0f - rk1) * inv1mr;
        tabB[tid] = (r - (float)(tid + 1) * rk1 + (float)tid * rk1 * r)
                    * (inv1mr * inv1mr);
    }
    for (int q = tid; q < COLS * PITCH; q += NTHREADS) {
        (&depD[0][0])[q] = 0.0f;
        (&depU[0][0])[q] = 0.0f;
    }

    // block min/max clamp exactly as reference
    const float bmn = wmin_in[n];
    const float bmx = wmax_in[n];
    const float wmn = fminf(bmn, bmx - 1e-6f);
    const float wmx = fmaxf(bmx, wmn + 1e-6f);
    const float scale = wmx - wmn;
    const float invsc = 1.0f / (scale + 1e-6f);

    __syncthreads();

    const int br = n >> 3, bc = n & 7;
    const int Cb = bc * 128 + slab * COLS;

    // phase 1: per-element closed-form softmax; float4-vectorized IO
    #pragma unroll
    for (int e = 0; e < 2; ++e) {
        const int row = (tid >> 2) + e * 64;   // 0..127
        const int c0  = (tid & 3) * 4;         // 0,4,8,12
        const int R = br * 128 + row;
        const int C = Cb + c0;
        const float4 x4 = *reinterpret_cast<const float4*>(Wt + (size_t)R * 1024 + C);
        float xs[4] = {x4.x, x4.y, x4.z, x4.w};
        float dq[4];
        #pragma unroll
        for (int u = 0; u < 4; ++u) {
            const float p = (xs[u] - wmn) * invsc * 255.0f;   // in [0, 255)
            int k = (int)p;
            k = (k > 254) ? 254 : k;
            const float f   = p - (float)k;
            const float rf  = exp2f(L2R * f);          // r^f
            const float r1f = exp2f(L2R * (1.0f - f)); // r^{1-f}
            const int   ku  = 254 - k;
            const float Ak = tabA[k],  Bk = tabB[k];
            const float Au = tabA[ku], Bu = tabB[ku];
            const float S  = rf * Ak + r1f * Au;
            const float Wn = rf * ((float)k * Ak - Bk)
                           + r1f * ((float)(k + 1) * Au + Bu);
            const float invS = 1.0f / S;
            dq[u] = (Wn * invS * (1.0f / 255.0f)) * scale + wmn;
            const int c = c0 + u;
            atomicAdd(&depD[c][k],     rf  * invS);
            atomicAdd(&depU[c][k + 1], r1f * invS);
        }
        float4 o4; o4.x = dq[0]; o4.y = dq[1]; o4.z = dq[2]; o4.w = dq[3];
        *reinterpret_cast<float4*>(dq_out + (size_t)R * 1024 + C) = o4;
    }

    __syncthreads();

    // phase 2a: chunk-local geometric scans; thread = (dir, col, chunk)
    {
        const int dir = tid >> 7;         // 0: down (hi->lo), 1: up (lo->hi)
        const int col = (tid >> 3) & 15;
        const int ch  = tid & 7;
        float* arr = dir ? &depU[col][0] : &depD[col][0];
        float v = 0.0f;
        if (dir == 0) {
            #pragma unroll
            for (int m = 0; m < 32; ++m) {
                const int l = ch * 32 + 31 - m;
                v = v * r + arr[l];
                arr[l] = v;
            }
        } else {
            #pragma unroll
            for (int m = 0; m < 32; ++m) {
                const int l = ch * 32 + m;
                v = v * r + arr[l];
                arr[l] = v;
            }
        }
    }
    __syncthreads();

    // phase 2b: serial carry propagation across 8 chunks (32 tasks)
    const float r32 = exp2f(L2R * 32.0f);
    if (tid < 32) {
        const int dir = tid >> 4;
        const int col = tid & 15;
        float* arr = dir ? &depU[col][0] : &depD[col][0];
        float cv = 0.0f;
        if (dir == 0) {
            for (int ch = 7; ch >= 0; --ch) {
                carry[dir][col][ch] = cv;            // carry entering from right
                cv = arr[ch * 32] + cv * r32;        // full value at chunk low end
            }
        } else {
            for (int ch = 0; ch < 8; ++ch) {
                carry[dir][col][ch] = cv;            // carry entering from left
                cv = arr[ch * 32 + 31] + cv * r32;   // full value at chunk high end
            }
        }
    }
    __syncthreads();

    // phase 2c: apply carries
    {
        const int dir = tid >> 7;
        const int col = (tid >> 3) & 15;
        const int ch  = tid & 7;
        const float cv = carry[dir][col][ch];
        float* arr = dir ? &depU[col][0] : &depD[col][0];
        if (cv != 0.0f) {
            float m = cv * r;
            if (dir == 0) {
                #pragma unroll
                for (int i = 0; i < 32; ++i) { arr[ch * 32 + 31 - i] += m; m *= r; }
            } else {
                #pragma unroll
                for (int i = 0; i < 32; ++i) { arr[ch * 32 + i] += m; m *= r; }
            }
        }
    }
    __syncthreads();

    // phase 3: entropy partial over this slab's 16x256 bins
    float hsum = 0.0f;
    const float invDen = 1.0f / 16384.0f;   // per-block mass = BS*BS (softmax sums to 1)
    for (int q = tid; q < COLS * LVL; q += NTHREADS) {
        const int c = q >> 8, l = q & 255;
        const float b  = depD[c][l] + depU[c][l];
        const float ph = b * invDen;
        hsum -= ph * logf(ph + 1e-6f);
    }
    #pragma unroll
    for (int off = 32; off > 0; off >>= 1) hsum += __shfl_down(hsum, off);
    if ((tid & 63) == 0) wred[tid >> 6] = hsum;
    __syncthreads();
    if (tid == 0) partials[wg] = wred[0] + wred[1] + wred[2] + wred[3];
}

__global__ __launch_bounds__(NTHREADS)
void bq_finish(const float* __restrict__ partials, float* __restrict__ ent_out)
{
    const int tid = threadIdx.x;
    float v = partials[tid] + partials[tid + 256];
    #pragma unroll
    for (int off = 32; off > 0; off >>= 1) v += __shfl_down(v, off);
    __shared__ float buf[4];
    if ((tid & 63) == 0) buf[tid >> 6] = v;
    __syncthreads();
    if (tid == 0) ent_out[0] = buf[0] + buf[1] + buf[2] + buf[3];
}

extern "C" void kernel_launch(void* const* d_in, const int* in_sizes, int n_in,
                              void* d_out, int out_size, void* d_ws, size_t ws_size,
                              hipStream_t stream)
{
    const float* Wt  = (const float*)d_in[0];   // weight [1024*1024]
    const float* wmn = (const float*)d_in[1];   // w_min [64]
    const float* wmx = (const float*)d_in[2];   // w_max [64]
    float* out = (float*)d_out;                 // [1048576 dequant] + [1 entropy]
    float* partials = (float*)d_ws;             // 512 floats

    bq_main<<<512, NTHREADS, 0, stream>>>(Wt, wmn, wmx, out, partials);
    bq_finish<<<1, NTHREADS, 0, stream>>>(partials, out + 1048576);
}